// Round 14
// baseline (2176.175 us; speedup 1.0000x reference)
//
#include <hip/hip_runtime.h>
#include <hip/hip_bf16.h>

#define V_  32000
#define E_  512
#define H_  1024
#define B_  16
#define T_  256
#define H3  3072

#define AGENT_LD(p)    __hip_atomic_load((p),  __ATOMIC_RELAXED, __HIP_MEMORY_SCOPE_AGENT)
#define AGENT_ST(p, v) __hip_atomic_store((p), (v), __ATOMIC_RELAXED, __HIP_MEMORY_SCOPE_AGENT)

typedef __attribute__((ext_vector_type(8))) short bf16x8;
typedef __attribute__((ext_vector_type(4))) float f32x4;

#define GLDS16(gp, lp) __builtin_amdgcn_global_load_lds( \
    (const __attribute__((address_space(1))) unsigned int*)(gp), \
    (__attribute__((address_space(3))) unsigned int*)(lp), 16, 0, 0)

__device__ __forceinline__ void split_f32(float v, unsigned short& hi, unsigned short& lo) {
  const __hip_bfloat16 hb = __float2bfloat16(v);
  hi = *(const unsigned short*)&hb;
  const __hip_bfloat16 lb = __float2bfloat16(v - __bfloat162float(hb));
  lo = *(const unsigned short*)&lb;
}
__device__ __forceinline__ float join_bf(unsigned short hi, unsigned short lo) {
  return __uint_as_float((unsigned)hi << 16) + __uint_as_float((unsigned)lo << 16);
}

// ---------------- embedding gather + hi/lo split (writes t-major rows) ----------------
__global__ __launch_bounds__(128) void k_embed_split(const int* __restrict__ x,
                                                     const float* __restrict__ emb,
                                                     unsigned short* __restrict__ hi,
                                                     unsigned short* __restrict__ lo) {
  const int rin = blockIdx.x;                  // b*T + t (x layout)
  const int b = rin >> 8, t = rin & 255;
  const int orow = t * 16 + b;                 // t-major
  const int idx = x[rin];
  const float4 v = ((const float4*)(emb + (size_t)idx * E_))[threadIdx.x];
  const float f[4] = {v.x, v.y, v.z, v.w};
  unsigned short hh[4], ll[4];
  #pragma unroll
  for (int k = 0; k < 4; ++k) split_f32(f[k], hh[k], ll[k]);
  ushort4 h4; h4.x = hh[0]; h4.y = hh[1]; h4.z = hh[2]; h4.w = hh[3];
  ushort4 l4; l4.x = ll[0]; l4.y = ll[1]; l4.z = ll[2]; l4.w = ll[3];
  ((ushort4*)(hi + (size_t)orow * E_))[threadIdx.x] = h4;
  ((ushort4*)(lo + (size_t)orow * E_))[threadIdx.x] = l4;
}

// ---------------- transpose Wh0 [1024][3072] -> WhTb [3072][1024] bf16 ----------------
__global__ __launch_bounds__(256) void k_transpose_b16(const float* __restrict__ W,
                                                       unsigned short* __restrict__ WTb) {
  __shared__ float tile[32][33];
  const int c0 = blockIdx.x * 32, r0 = blockIdx.y * 32;
  const int tx = threadIdx.x & 31, ty = threadIdx.x >> 5;
  #pragma unroll
  for (int i = ty; i < 32; i += 8)
    tile[i][tx] = W[(size_t)(r0 + i) * H3 + c0 + tx];
  __syncthreads();
  #pragma unroll
  for (int i = ty; i < 32; i += 8) {
    const __hip_bfloat16 v = __float2bfloat16(tile[tx][i]);
    WTb[(size_t)(c0 + i) * H_ + r0 + tx] = *(const unsigned short*)&v;
  }
}

// ---------------- transpose + hi/lo split ----------------
__global__ __launch_bounds__(256) void k_transpose_split(const float* __restrict__ W, int ldw,
                                                         unsigned short* __restrict__ WThi,
                                                         unsigned short* __restrict__ WTlo,
                                                         int R) {
  __shared__ float tile[32][33];
  const int c0 = blockIdx.x * 32, r0 = blockIdx.y * 32;
  const int tx = threadIdx.x & 31, ty = threadIdx.x >> 5;
  #pragma unroll
  for (int i = ty; i < 32; i += 8)
    tile[i][tx] = W[(size_t)(r0 + i) * ldw + c0 + tx];
  __syncthreads();
  #pragma unroll
  for (int i = ty; i < 32; i += 8) {
    unsigned short h, l;
    split_f32(tile[tx][i], h, l);
    WThi[(size_t)(c0 + i) * R + r0 + tx] = h;
    WTlo[(size_t)(c0 + i) * R + r0 + tx] = l;
  }
}

// ---------------- bias concat ----------------
__global__ __launch_bounds__(512) void k_catbias(const float* __restrict__ a,
                                                 const float* __restrict__ b,
                                                 float* __restrict__ o) {
  const int i = blockIdx.x * 512 + threadIdx.x;
  o[i] = (i < H3) ? a[i] : b[i - H3];
}

// ---------------- split-bf16 MFMA GEMM (proven; optional t-major->b-major C remap) ----------------
__global__ __launch_bounds__(256, 2) void k_gemm_mfma(
    const unsigned short* __restrict__ Ahi, const unsigned short* __restrict__ Alo,
    const unsigned short* __restrict__ BThi, const unsigned short* __restrict__ BTlo,
    const float* __restrict__ bias, float* __restrict__ C,
    int MT, int NT, int K, int ldc, int remap) {
  __shared__ unsigned short sAhi[128 * 64], sAlo[128 * 64];
  __shared__ unsigned short sBhi[128 * 64], sBlo[128 * 64];

  const int bid = blockIdx.x;
  const int GROUPM = 8;
  const int group = bid / (GROUPM * NT);
  const int first = group * GROUPM;
  const int gsm = (MT - first < GROUPM) ? (MT - first) : GROUPM;
  const int rem = bid % (GROUPM * NT);
  const int pm = first + rem % gsm;
  const int pn = rem / gsm;
  const int bm = pm * 128, bn = pn * 128;

  const int tid = threadIdx.x;
  const int wv = tid >> 6, l = tid & 63;
  const int wr = wv >> 1, wc = wv & 1;
  const int frow = l & 15;
  const int ksl  = l >> 4;

  f32x4 acc[4][4];
  #pragma unroll
  for (int a = 0; a < 4; ++a)
    #pragma unroll
    for (int b = 0; b < 4; ++b) acc[a][b] = (f32x4){0.f, 0.f, 0.f, 0.f};

  for (int k0 = 0; k0 < K; k0 += 64) {
    __syncthreads();
    #pragma unroll
    for (int p = 0; p < 4; ++p) {
      const int obase = ((p << 2) + wv) << 10;
      const int row = ((obase >> 7)) + (l >> 3);
      const int slot = l & 7;
      const int gcol = k0 + ((slot ^ (row & 7)) << 3);
      const size_t ga = (size_t)(bm + row) * K + gcol;
      const size_t gb = (size_t)(bn + row) * K + gcol;
      GLDS16(Ahi + ga, (char*)sAhi + obase);
      GLDS16(Alo + ga, (char*)sAlo + obase);
      GLDS16(BThi + gb, (char*)sBhi + obase);
      GLDS16(BTlo + gb, (char*)sBlo + obase);
    }
    __syncthreads();
    #pragma unroll
    for (int kk = 0; kk < 2; ++kk) {
      bf16x8 ah[4], al[4], bh[4], bl[4];
      #pragma unroll
      for (int f = 0; f < 4; ++f) {
        const int ar = wr * 64 + f * 16 + frow;
        const int aoff = ar * 128 + ((((kk << 2) + ksl) ^ (ar & 7)) << 4);
        ah[f] = *(const bf16x8*)((const char*)sAhi + aoff);
        al[f] = *(const bf16x8*)((const char*)sAlo + aoff);
        const int br_ = wc * 64 + f * 16 + frow;
        const int boff = br_ * 128 + ((((kk << 2) + ksl) ^ (br_ & 7)) << 4);
        bh[f] = *(const bf16x8*)((const char*)sBhi + boff);
        bl[f] = *(const bf16x8*)((const char*)sBlo + boff);
      }
      #pragma unroll
      for (int fm = 0; fm < 4; ++fm)
        #pragma unroll
        for (int fn = 0; fn < 4; ++fn) {
          acc[fm][fn] = __builtin_amdgcn_mfma_f32_16x16x32_bf16(ah[fm], bh[fn], acc[fm][fn], 0, 0, 0);
          acc[fm][fn] = __builtin_amdgcn_mfma_f32_16x16x32_bf16(ah[fm], bl[fn], acc[fm][fn], 0, 0, 0);
          acc[fm][fn] = __builtin_amdgcn_mfma_f32_16x16x32_bf16(al[fm], bh[fn], acc[fm][fn], 0, 0, 0);
        }
    }
  }

  const int crow0 = bm + wr * 64 + (l >> 4) * 4;
  const int ccol0 = bn + wc * 64 + (l & 15);
  #pragma unroll
  for (int fn = 0; fn < 4; ++fn) {
    const int col = ccol0 + fn * 16;
    const float bv = bias[col];
    #pragma unroll
    for (int fm = 0; fm < 4; ++fm) {
      const int r0 = crow0 + fm * 16;
      #pragma unroll
      for (int i = 0; i < 4; ++i) {
        const int rr = r0 + i;
        const int orow = remap ? ((rr & 15) * T_ + (rr >> 4)) : rr;  // t-major -> b-major
        C[(size_t)orow * ldc + col] = acc[fm][fn][i] + bv;
      }
    }
  }
}

// ---------------- layer-0 recurrence: 32 MFMA WGs + dataflow tags; 224 helper WGs ----------------
// t-major H0 (row = t*16+b): step t's h is one contiguous 32KB block per plane, written
// exactly once (AGENT_ST packed u32) -> H0 IS the exchange buffer (no hbuf, WAR vacuous).
// tag[p][c] at bar[(p*32+c)*32] (1 writer, 1 reading wave). RULE #18: sched_barrier(0)
// after inline-asm vmcnt(0) (MFMA consumers are register-only).
__global__ __launch_bounds__(512, 1) void k_recur3(
    const unsigned short* __restrict__ WhTb,   // [3072][1024] bf16
    const float* __restrict__ GX0,             // [4096][3072] f32, t-major rows
    const float* __restrict__ bh0,
    unsigned short* __restrict__ H0hi,         // [4096][1024] t-major
    unsigned short* __restrict__ H0lo,
    unsigned* __restrict__ bar,
    const float* __restrict__ Wx1,
    const float* __restrict__ Wh1,
    unsigned short* __restrict__ BThi,
    unsigned short* __restrict__ BTlo) {
  __shared__ float red[12288];                 // 48 KB
  const int tid = threadIdx.x;
  const int wg = blockIdx.x;

  if (wg >= 32) {
    // ---------- helper: static-striped Wx1/Wh1 transpose+split into BT, then exit ----------
    float* tile = red;                          // [32][33]
    const int ty = tid >> 5, tx = tid & 31;     // ty in [0,16)
    for (int tix = wg - 32; tix < 6144; tix += 224) {
      const int job = tix >= 3072;
      const int tt = job ? tix - 3072 : tix;
      const int c0 = (tt % 96) * 32, r0 = (tt / 96) * 32;
      const float* W = job ? Wh1 : Wx1;
      unsigned short* Dhi = BThi + (job ? (size_t)H3 * H_ : 0);
      unsigned short* Dlo = BTlo + (job ? (size_t)H3 * H_ : 0);
      __syncthreads();
      tile[ty * 33 + tx]        = W[(size_t)(r0 + ty) * H3 + c0 + tx];
      tile[(ty + 16) * 33 + tx] = W[(size_t)(r0 + ty + 16) * H3 + c0 + tx];
      __syncthreads();
      #pragma unroll
      for (int s = 0; s < 2; ++s) {
        const int i = ty + s * 16;
        unsigned short h, l;
        split_f32(tile[tx * 33 + i], h, l);
        Dhi[(size_t)(c0 + i) * H_ + r0 + tx] = h;
        Dlo[(size_t)(c0 + i) * H_ + r0 + tx] = l;
      }
    }
    return;
  }

  // ---------- participant WG `rank` owns h-cols [32*rank, 32*rank+32) ----------
  const int rank = wg;
  const int wv = tid >> 6, l = tid & 63;
  const int b  = tid >> 5, jj = tid & 31;      // thread -> (batch b, col-offset jj)
  const int col = rank * 32 + jj;

  // one-time Wh B-frags into VGPRs (layouts identical to proven k_gemm_mfma)
  bf16x8 breg[6][4];
  #pragma unroll
  for (int nf = 0; nf < 6; ++nf) {
    const int g = nf >> 1, h2 = nf & 1;
    const int bcol = g * 1024 + rank * 32 + h2 * 16 + (l & 15);
    #pragma unroll
    for (int kf = 0; kf < 4; ++kf)
      breg[nf][kf] = *(const bf16x8*)(WhTb + (size_t)bcol * 1024 + wv * 128 + kf * 32 + ((l >> 4) << 3));
  }
  const float bhr = bh0[col], bhz = bh0[1024 + col], bhn = bh0[2048 + col];

  float xr, xz, xn;
  {
    const size_t g0 = (size_t)(0 * 16 + b) * H3;    // t=0 prefetch (t-major row)
    xr = GX0[g0 + col]; xz = GX0[g0 + 1024 + col]; xn = GX0[g0 + 2048 + col];
  }
  float hprev = 0.f;

  for (int t = 0; t < T_; ++t) {
    bf16x8 ahi[4], alo[4];
    if (t == 0) {
      #pragma unroll
      for (int kf = 0; kf < 4; ++kf) {
        ahi[kf] = (bf16x8){0, 0, 0, 0, 0, 0, 0, 0};
        alo[kf] = (bf16x8){0, 0, 0, 0, 0, 0, 0, 0};
      }
    } else {
      // ---- per-wave dataflow wait: this wave's 4 producers must have published t ----
      const unsigned* tp = &bar[(unsigned)((4 * wv + (l & 3)) * 32 + rank) * 32];
      int guard = 0;
      for (;;) {
        const unsigned v = AGENT_LD(tp);
        if (__all(v >= (unsigned)t)) break;
        if (++guard > 10000000) break;         // hang guard -> degrade to wrong answer
      }
      // ---- A-frags straight from H0 planes (t-1 block is contiguous 32KB) ----
      const size_t aoff = (size_t)(t - 1) * 32768 + ((l & 15) * 2048)
                          + ((wv * 128 + ((l >> 4) << 3)) << 1);
      const char* abh = (const char*)H0hi + aoff;
      const char* abl = (const char*)H0lo + aoff;
      #pragma unroll
      for (int kf = 0; kf < 4; ++kf) {
        asm volatile("global_load_dwordx4 %0, %1, off sc0 sc1" : "=v"(ahi[kf]) : "v"(abh + kf * 64));
        asm volatile("global_load_dwordx4 %0, %1, off sc0 sc1" : "=v"(alo[kf]) : "v"(abl + kf * 64));
      }
      asm volatile("s_waitcnt vmcnt(0)" ::: "memory");
      __builtin_amdgcn_sched_barrier(0);       // MFMA must not hoist past the waitcnt
    }

    #pragma unroll
    for (int nf = 0; nf < 6; ++nf) {
      f32x4 a4 = (f32x4){0.f, 0.f, 0.f, 0.f};
      #pragma unroll
      for (int kf = 0; kf < 4; ++kf) {
        a4 = __builtin_amdgcn_mfma_f32_16x16x32_bf16(ahi[kf], breg[nf][kf], a4, 0, 0, 0);
        a4 = __builtin_amdgcn_mfma_f32_16x16x32_bf16(alo[kf], breg[nf][kf], a4, 0, 0, 0);
      }
      *(f32x4*)&red[(((wv * 6 + nf) << 6) + l) << 2] = a4;
    }
    __syncthreads();   // all 8 waves passed tag-wait t (RAW gate; WAR vacuous in t-major)

    // ---- reduce 8 wave-partials + gates; thread = (b, jj) ----
    const int h2 = jj >> 4, f = jj & 15;
    const int lp = ((b >> 2) << 4) + f, ii = b & 3;
    float p3[3];
    #pragma unroll
    for (int g = 0; g < 3; ++g) {
      const int nf = g * 2 + h2;
      float s = 0.f;
      #pragma unroll
      for (int w8 = 0; w8 < 8; ++w8)
        s += red[((((w8 * 6 + nf) << 6) + lp) << 2) + ii];
      p3[g] = s;
    }
    const float r = 1.f / (1.f + expf(-(xr + p3[0] + bhr)));
    const float z = 1.f / (1.f + expf(-(xz + p3[1] + bhz)));
    const float n = tanhf(xn + r * (p3[2] + bhn));
    const float hnew = (1.f - z) * n + z * hprev;
    hprev = hnew;
    unsigned short hh, hl;
    split_f32(hnew, hh, hl);

    // ---- publish h to H0 planes (packed col-pairs, AGENT_ST) ----
    {
      const unsigned tmp = (unsigned)hh | ((unsigned)hl << 16);
      const unsigned nb = __shfl_xor(tmp, 1);
      if ((jj & 1) == 0) {
        const unsigned hw = (tmp & 0xffffu) | ((nb & 0xffffu) << 16);
        const unsigned lw = (tmp >> 16) | (nb & 0xffff0000u);
        const size_t u32i = (((size_t)(t * 16 + b) << 10) + col) >> 1;
        AGENT_ST((unsigned*)H0hi + u32i, hw);
        AGENT_ST((unsigned*)H0lo + u32i, lw);
      }
    }

    if (t + 1 < T_) {
      __syncthreads();                         // vmcnt(0) drain: h stores at LLC
      if (tid < 32) AGENT_ST(&bar[(unsigned)(rank * 32 + tid) * 32], (unsigned)(t + 1));
      {                                        // GX0 prefetch for t+1 (off critical path)
        const size_t g0 = (size_t)((t + 1) * 16 + b) * H3;
        xr = GX0[g0 + col]; xz = GX0[g0 + 1024 + col]; xn = GX0[g0 + 2048 + col];
      }
    }
  }
}

// ---------------- layer-1 elementwise: G1 [rows][6144] t-major, hi/lo in/out ----------------
__global__ __launch_bounds__(256) void k_gru1(const float* __restrict__ G1,
                                              const unsigned short* __restrict__ H0hi,
                                              const unsigned short* __restrict__ H0lo,
                                              unsigned short* __restrict__ H1hi,
                                              unsigned short* __restrict__ H1lo, int row0) {
  const int lrow = blockIdx.x;
  const size_t row = (size_t)row0 + lrow;
  const float* g = G1 + (size_t)lrow * 6144;
  for (int j = threadIdx.x; j < H_; j += 256) {
    const float xr = g[j], xz = g[1024 + j], xn = g[2048 + j];
    const float hr = g[3072 + j], hz = g[4096 + j], hn = g[5120 + j];
    const size_t idx = (row << 10) + j;
    const float h = join_bf(H0hi[idx], H0lo[idx]);
    const float r = 1.f / (1.f + expf(-(xr + hr)));
    const float z = 1.f / (1.f + expf(-(xz + hz)));
    const float n = tanhf(xn + r * hn);
    const float hnew = (1.f - z) * n + z * h;
    unsigned short hh, hl;
    split_f32(hnew, hh, hl);
    H1hi[idx] = hh;
    H1lo[idx] = hl;
  }
}

// ---------------- final hidden: out[2][B][H] from t-major hi/lo ----------------
__global__ __launch_bounds__(256) void k_hidden(const unsigned short* __restrict__ H0hi,
                                                const unsigned short* __restrict__ H0lo,
                                                const unsigned short* __restrict__ H1hi,
                                                const unsigned short* __restrict__ H1lo,
                                                float* __restrict__ out) {
  const int i = blockIdx.x * 256 + threadIdx.x;
  const int l = i >> 14;
  const int b = (i >> 10) & 15;
  const int j = i & 1023;
  const size_t idx = ((size_t)(255 * 16 + b) << 10) + j;   // t = T-1, t-major
  out[i] = l ? join_bf(H1hi[idx], H1lo[idx]) : join_bf(H0hi[idx], H0lo[idx]);
}

extern "C" void kernel_launch(void* const* d_in, const int* in_sizes, int n_in,
                              void* d_out, int out_size, void* d_ws, size_t ws_size,
                              hipStream_t stream) {
  const int*   x   = (const int*)d_in[0];
  const float* emb = (const float*)d_in[1];
  const float* Wx0 = (const float*)d_in[2];
  const float* Wh0 = (const float*)d_in[3];
  const float* bx0 = (const float*)d_in[4];
  const float* bh0 = (const float*)d_in[5];
  const float* Wx1 = (const float*)d_in[6];
  const float* Wh1 = (const float*)d_in[7];
  const float* bx1 = (const float*)d_in[8];
  const float* bh1 = (const float*)d_in[9];
  const float* fcW = (const float*)d_in[10];
  const float* fcb = (const float*)d_in[11];
  float* out = (float*)d_out;

  char* ws = (char*)d_ws;
  const size_t MB = 1024 * 1024;
  // persistent hi/lo hidden states (t-major rows)
  unsigned short* H0hi = (unsigned short*)(ws + 0);        // 8 MB [4096][1024]
  unsigned short* H0lo = (unsigned short*)(ws + 8 * MB);
  unsigned short* H1hi = (unsigned short*)(ws + 16 * MB);
  unsigned short* H1lo = (unsigned short*)(ws + 24 * MB);
  char* S = ws + 32 * MB;
  // phase A/B
  unsigned short* WhTb  = (unsigned short*)(S);            // 6 MB
  float*          GX0   = (float*)(S + 8 * MB);            // 48 MB (t-major)
  unsigned short* EmbHi = (unsigned short*)(S + 56 * MB);  // 4 MB (dead after GX0 gemm)
  unsigned short* EmbLo = (unsigned short*)(S + 60 * MB);  // 4 MB
  unsigned short* Wx0Thi= (unsigned short*)(S + 64 * MB);  // 3 MB
  unsigned short* Wx0Tlo= (unsigned short*)(S + 67 * MB);  // 3 MB
  // written by helper WGs during k_recur3 (over the corpses above):
  unsigned short* BThi  = (unsigned short*)(S + 56 * MB);  // 12 MB [6144][1024] (Wx1T|Wh1T)
  unsigned short* BTlo  = (unsigned short*)(S + 68 * MB);  // 12 MB
  unsigned*       bar   = (unsigned*)(S + 80 * MB);        // 128 KB tag matrix
  float*          b1cat = (float*)(S + 80 * MB + 131072);  // 24 KB
  // phase C (GX0 corpse)
  float* G1 = (float*)(S + 8 * MB);                        // 48 MB [2048][6144]
  // phase D
  unsigned short* fcThi = (unsigned short*)(S);            // 31.25 MB (16000x1024)
  unsigned short* fcTlo = (unsigned short*)(S + 32 * MB);  // 31.25 MB

  // ---- phase A: embeddings (split, t-major), Wh0->bf16, Wx0 split-T, GX0 via MFMA ----
  k_embed_split<<<dim3(B_ * T_), dim3(128), 0, stream>>>(x, emb, EmbHi, EmbLo);
  k_transpose_b16<<<dim3(H3 / 32, H_ / 32), dim3(256), 0, stream>>>(Wh0, WhTb);
  k_transpose_split<<<dim3(H3 / 32, E_ / 32), dim3(256), 0, stream>>>(Wx0, H3, Wx0Thi, Wx0Tlo, E_);
  k_gemm_mfma<<<dim3(32 * 24), dim3(256), 0, stream>>>(
      EmbHi, EmbLo, Wx0Thi, Wx0Tlo, bx0, GX0, 32, 24, E_, H3, 0);
  k_catbias<<<dim3(12), dim3(512), 0, stream>>>(bx1, bh1, b1cat);

  // ---- phase B: recurrence (WGs 0-31) + Wx1/Wh1 transposes (WGs 32-255) ----
  hipMemsetAsync(bar, 0, 131072, stream);
  {
    void* args[] = {(void*)&WhTb, (void*)&GX0, (void*)&bh0, (void*)&H0hi, (void*)&H0lo,
                    (void*)&bar, (void*)&Wx1, (void*)&Wh1, (void*)&BThi, (void*)&BTlo};
    hipLaunchCooperativeKernel((const void*)k_recur3, dim3(256), dim3(512), args, 0, stream);
  }

  // ---- phase C: layer 1, one merged GEMM per chunk (N = 6144) ----
  for (int chunk = 0; chunk < 2; ++chunk) {
    const unsigned short* Ah = H0hi + (size_t)chunk * 2048 * H_;
    const unsigned short* Al = H0lo + (size_t)chunk * 2048 * H_;
    k_gemm_mfma<<<dim3(16 * 48), dim3(256), 0, stream>>>(
        Ah, Al, BThi, BTlo, b1cat, G1, 16, 48, H_, 6144, 0);
    k_gru1<<<dim3(2048), dim3(256), 0, stream>>>(G1, H0hi, H0lo, H1hi, H1lo, chunk * 2048);
  }

  // ---- phase D: FC via split-bf16 MFMA, 2 N-chunks of 16000, b-major epilogue remap ----
  for (int chunk = 0; chunk < 2; ++chunk) {
    const float* Wc = fcW + (size_t)chunk * 16000;
    k_transpose_split<<<dim3(16000 / 32, H_ / 32), dim3(256), 0, stream>>>(
        Wc, V_, fcThi, fcTlo, H_);
    k_gemm_mfma<<<dim3(32 * 125), dim3(256), 0, stream>>>(
        H1hi, H1lo, fcThi, fcTlo, fcb + (size_t)chunk * 16000,
        out + (size_t)chunk * 16000, 32, 125, H_, V_, 1);
  }

  // ---- final hidden ----
  k_hidden<<<dim3(32768 / 256), dim3(256), 0, stream>>>(H0hi, H0lo, H1hi, H1lo,
                                                        out + (size_t)B_ * T_ * V_);
}

// Round 15
// 1791.673 us; speedup vs baseline: 1.2146x; 1.2146x over previous
//
#include <hip/hip_runtime.h>
#include <hip/hip_bf16.h>

#define V_  32000
#define E_  512
#define H_  1024
#define B_  16
#define T_  256
#define H3  3072

#define AGENT_LD(p)    __hip_atomic_load((p),  __ATOMIC_RELAXED, __HIP_MEMORY_SCOPE_AGENT)
#define AGENT_ST(p, v) __hip_atomic_store((p), (v), __ATOMIC_RELAXED, __HIP_MEMORY_SCOPE_AGENT)

typedef __attribute__((ext_vector_type(8))) short bf16x8;
typedef __attribute__((ext_vector_type(8))) _Float16 f16x8;
typedef __attribute__((ext_vector_type(4))) float f32x4;

#define GLDS16(gp, lp) __builtin_amdgcn_global_load_lds( \
    (const __attribute__((address_space(1))) unsigned int*)(gp), \
    (__attribute__((address_space(3))) unsigned int*)(lp), 16, 0, 0)

__device__ __forceinline__ void split_f32(float v, unsigned short& hi, unsigned short& lo) {
  const __hip_bfloat16 hb = __float2bfloat16(v);
  hi = *(const unsigned short*)&hb;
  const __hip_bfloat16 lb = __float2bfloat16(v - __bfloat162float(hb));
  lo = *(const unsigned short*)&lb;
}
__device__ __forceinline__ float join_bf(unsigned short hi, unsigned short lo) {
  return __uint_as_float((unsigned)hi << 16) + __uint_as_float((unsigned)lo << 16);
}

// ---------------- embedding gather + hi/lo split (writes t-major rows) ----------------
__global__ __launch_bounds__(128) void k_embed_split(const int* __restrict__ x,
                                                     const float* __restrict__ emb,
                                                     unsigned short* __restrict__ hi,
                                                     unsigned short* __restrict__ lo) {
  const int rin = blockIdx.x;                  // b*T + t (x layout)
  const int b = rin >> 8, t = rin & 255;
  const int orow = t * 16 + b;                 // t-major
  const int idx = x[rin];
  const float4 v = ((const float4*)(emb + (size_t)idx * E_))[threadIdx.x];
  const float f[4] = {v.x, v.y, v.z, v.w};
  unsigned short hh[4], ll[4];
  #pragma unroll
  for (int k = 0; k < 4; ++k) split_f32(f[k], hh[k], ll[k]);
  ushort4 h4; h4.x = hh[0]; h4.y = hh[1]; h4.z = hh[2]; h4.w = hh[3];
  ushort4 l4; l4.x = ll[0]; l4.y = ll[1]; l4.z = ll[2]; l4.w = ll[3];
  ((ushort4*)(hi + (size_t)orow * E_))[threadIdx.x] = h4;
  ((ushort4*)(lo + (size_t)orow * E_))[threadIdx.x] = l4;
}

// ---------------- transpose Wh0 [1024][3072] -> WhTb [3072][1024] bf16 ----------------
__global__ __launch_bounds__(256) void k_transpose_b16(const float* __restrict__ W,
                                                       unsigned short* __restrict__ WTb) {
  __shared__ float tile[32][33];
  const int c0 = blockIdx.x * 32, r0 = blockIdx.y * 32;
  const int tx = threadIdx.x & 31, ty = threadIdx.x >> 5;
  #pragma unroll
  for (int i = ty; i < 32; i += 8)
    tile[i][tx] = W[(size_t)(r0 + i) * H3 + c0 + tx];
  __syncthreads();
  #pragma unroll
  for (int i = ty; i < 32; i += 8) {
    const __hip_bfloat16 v = __float2bfloat16(tile[tx][i]);
    WTb[(size_t)(c0 + i) * H_ + r0 + tx] = *(const unsigned short*)&v;
  }
}

// ---------------- transpose + hi/lo split ----------------
__global__ __launch_bounds__(256) void k_transpose_split(const float* __restrict__ W, int ldw,
                                                         unsigned short* __restrict__ WThi,
                                                         unsigned short* __restrict__ WTlo,
                                                         int R) {
  __shared__ float tile[32][33];
  const int c0 = blockIdx.x * 32, r0 = blockIdx.y * 32;
  const int tx = threadIdx.x & 31, ty = threadIdx.x >> 5;
  #pragma unroll
  for (int i = ty; i < 32; i += 8)
    tile[i][tx] = W[(size_t)(r0 + i) * ldw + c0 + tx];
  __syncthreads();
  #pragma unroll
  for (int i = ty; i < 32; i += 8) {
    unsigned short h, l;
    split_f32(tile[tx][i], h, l);
    WThi[(size_t)(c0 + i) * R + r0 + tx] = h;
    WTlo[(size_t)(c0 + i) * R + r0 + tx] = l;
  }
}

// ---------------- transpose to fp16: W [R][ldw] f32 -> WT [C][R] fp16 ----------------
__global__ __launch_bounds__(256) void k_transpose_f16(const float* __restrict__ W, int ldw,
                                                       _Float16* __restrict__ WT, int R) {
  __shared__ float tile[32][33];
  const int c0 = blockIdx.x * 32, r0 = blockIdx.y * 32;
  const int tx = threadIdx.x & 31, ty = threadIdx.x >> 5;
  #pragma unroll
  for (int i = ty; i < 32; i += 8)
    tile[i][tx] = W[(size_t)(r0 + i) * ldw + c0 + tx];
  __syncthreads();
  #pragma unroll
  for (int i = ty; i < 32; i += 8)
    WT[(size_t)(c0 + i) * R + r0 + tx] = (_Float16)tile[tx][i];
}

// ---------------- bias concat ----------------
__global__ __launch_bounds__(512) void k_catbias(const float* __restrict__ a,
                                                 const float* __restrict__ b,
                                                 float* __restrict__ o) {
  const int i = blockIdx.x * 512 + threadIdx.x;
  o[i] = (i < H3) ? a[i] : b[i - H3];
}

// ---------------- split-bf16 MFMA GEMM (proven; used for GX0 + layer-1) ----------------
__global__ __launch_bounds__(256, 2) void k_gemm_mfma(
    const unsigned short* __restrict__ Ahi, const unsigned short* __restrict__ Alo,
    const unsigned short* __restrict__ BThi, const unsigned short* __restrict__ BTlo,
    const float* __restrict__ bias, float* __restrict__ C,
    int MT, int NT, int K, int ldc, int remap) {
  __shared__ unsigned short sAhi[128 * 64], sAlo[128 * 64];
  __shared__ unsigned short sBhi[128 * 64], sBlo[128 * 64];

  const int bid = blockIdx.x;
  const int GROUPM = 8;
  const int group = bid / (GROUPM * NT);
  const int first = group * GROUPM;
  const int gsm = (MT - first < GROUPM) ? (MT - first) : GROUPM;
  const int rem = bid % (GROUPM * NT);
  const int pm = first + rem % gsm;
  const int pn = rem / gsm;
  const int bm = pm * 128, bn = pn * 128;

  const int tid = threadIdx.x;
  const int wv = tid >> 6, l = tid & 63;
  const int wr = wv >> 1, wc = wv & 1;
  const int frow = l & 15;
  const int ksl  = l >> 4;

  f32x4 acc[4][4];
  #pragma unroll
  for (int a = 0; a < 4; ++a)
    #pragma unroll
    for (int b = 0; b < 4; ++b) acc[a][b] = (f32x4){0.f, 0.f, 0.f, 0.f};

  for (int k0 = 0; k0 < K; k0 += 64) {
    __syncthreads();
    #pragma unroll
    for (int p = 0; p < 4; ++p) {
      const int obase = ((p << 2) + wv) << 10;
      const int row = ((obase >> 7)) + (l >> 3);
      const int slot = l & 7;
      const int gcol = k0 + ((slot ^ (row & 7)) << 3);
      const size_t ga = (size_t)(bm + row) * K + gcol;
      const size_t gb = (size_t)(bn + row) * K + gcol;
      GLDS16(Ahi + ga, (char*)sAhi + obase);
      GLDS16(Alo + ga, (char*)sAlo + obase);
      GLDS16(BThi + gb, (char*)sBhi + obase);
      GLDS16(BTlo + gb, (char*)sBlo + obase);
    }
    __syncthreads();
    #pragma unroll
    for (int kk = 0; kk < 2; ++kk) {
      bf16x8 ah[4], al[4], bh[4], bl[4];
      #pragma unroll
      for (int f = 0; f < 4; ++f) {
        const int ar = wr * 64 + f * 16 + frow;
        const int aoff = ar * 128 + ((((kk << 2) + ksl) ^ (ar & 7)) << 4);
        ah[f] = *(const bf16x8*)((const char*)sAhi + aoff);
        al[f] = *(const bf16x8*)((const char*)sAlo + aoff);
        const int br_ = wc * 64 + f * 16 + frow;
        const int boff = br_ * 128 + ((((kk << 2) + ksl) ^ (br_ & 7)) << 4);
        bh[f] = *(const bf16x8*)((const char*)sBhi + boff);
        bl[f] = *(const bf16x8*)((const char*)sBlo + boff);
      }
      #pragma unroll
      for (int fm = 0; fm < 4; ++fm)
        #pragma unroll
        for (int fn = 0; fn < 4; ++fn) {
          acc[fm][fn] = __builtin_amdgcn_mfma_f32_16x16x32_bf16(ah[fm], bh[fn], acc[fm][fn], 0, 0, 0);
          acc[fm][fn] = __builtin_amdgcn_mfma_f32_16x16x32_bf16(ah[fm], bl[fn], acc[fm][fn], 0, 0, 0);
          acc[fm][fn] = __builtin_amdgcn_mfma_f32_16x16x32_bf16(al[fm], bh[fn], acc[fm][fn], 0, 0, 0);
        }
    }
  }

  const int crow0 = bm + wr * 64 + (l >> 4) * 4;
  const int ccol0 = bn + wc * 64 + (l & 15);
  #pragma unroll
  for (int fn = 0; fn < 4; ++fn) {
    const int col = ccol0 + fn * 16;
    const float bv = bias[col];
    #pragma unroll
    for (int fm = 0; fm < 4; ++fm) {
      const int r0 = crow0 + fm * 16;
      #pragma unroll
      for (int i = 0; i < 4; ++i) {
        const int rr = r0 + i;
        const int orow = remap ? ((rr & 15) * T_ + (rr >> 4)) : rr;
        C[(size_t)orow * ldc + col] = acc[fm][fn][i] + bv;
      }
    }
  }
}

// ---------------- single-pass fp16 MFMA GEMM (FC only; same structure, 2 streams) ----------------
__global__ __launch_bounds__(256, 4) void k_gemm_f16(
    const _Float16* __restrict__ A, const _Float16* __restrict__ BT,
    const float* __restrict__ bias, float* __restrict__ C,
    int MT, int NT, int K, int ldc, int remap) {
  __shared__ _Float16 sA[128 * 64], sB[128 * 64];

  const int bid = blockIdx.x;
  const int GROUPM = 8;
  const int group = bid / (GROUPM * NT);
  const int first = group * GROUPM;
  const int gsm = (MT - first < GROUPM) ? (MT - first) : GROUPM;
  const int rem = bid % (GROUPM * NT);
  const int pm = first + rem % gsm;
  const int pn = rem / gsm;
  const int bm = pm * 128, bn = pn * 128;

  const int tid = threadIdx.x;
  const int wv = tid >> 6, l = tid & 63;
  const int wr = wv >> 1, wc = wv & 1;
  const int frow = l & 15;
  const int ksl  = l >> 4;

  f32x4 acc[4][4];
  #pragma unroll
  for (int a = 0; a < 4; ++a)
    #pragma unroll
    for (int b = 0; b < 4; ++b) acc[a][b] = (f32x4){0.f, 0.f, 0.f, 0.f};

  for (int k0 = 0; k0 < K; k0 += 64) {
    __syncthreads();
    #pragma unroll
    for (int p = 0; p < 4; ++p) {
      const int obase = ((p << 2) + wv) << 10;
      const int row = ((obase >> 7)) + (l >> 3);
      const int slot = l & 7;
      const int gcol = k0 + ((slot ^ (row & 7)) << 3);
      GLDS16(A + (size_t)(bm + row) * K + gcol, (char*)sA + obase);
      GLDS16(BT + (size_t)(bn + row) * K + gcol, (char*)sB + obase);
    }
    __syncthreads();
    #pragma unroll
    for (int kk = 0; kk < 2; ++kk) {
      f16x8 a[4], b[4];
      #pragma unroll
      for (int f = 0; f < 4; ++f) {
        const int ar = wr * 64 + f * 16 + frow;
        a[f] = *(const f16x8*)((const char*)sA + ar * 128 + ((((kk << 2) + ksl) ^ (ar & 7)) << 4));
        const int br_ = wc * 64 + f * 16 + frow;
        b[f] = *(const f16x8*)((const char*)sB + br_ * 128 + ((((kk << 2) + ksl) ^ (br_ & 7)) << 4));
      }
      #pragma unroll
      for (int fm = 0; fm < 4; ++fm)
        #pragma unroll
        for (int fn = 0; fn < 4; ++fn)
          acc[fm][fn] = __builtin_amdgcn_mfma_f32_16x16x32_f16(a[fm], b[fn], acc[fm][fn], 0, 0, 0);
    }
  }

  const int crow0 = bm + wr * 64 + (l >> 4) * 4;
  const int ccol0 = bn + wc * 64 + (l & 15);
  #pragma unroll
  for (int fn = 0; fn < 4; ++fn) {
    const int col = ccol0 + fn * 16;
    const float bv = bias[col];
    #pragma unroll
    for (int fm = 0; fm < 4; ++fm) {
      const int r0 = crow0 + fm * 16;
      #pragma unroll
      for (int i = 0; i < 4; ++i) {
        const int rr = r0 + i;
        const int orow = remap ? ((rr & 15) * T_ + (rr >> 4)) : rr;
        C[(size_t)orow * ldc + col] = acc[fm][fn][i] + bv;
      }
    }
  }
}

// ---------------- layer-0 recurrence (round-13 proven, unchanged) ----------------
__global__ __launch_bounds__(512, 1) void k_recur3(
    const unsigned short* __restrict__ WhTb,   // [3072][1024] bf16
    const float* __restrict__ GX0,             // [4096][3072] f32, t-major rows
    const float* __restrict__ bh0,
    unsigned short* __restrict__ H0hi,         // [4096][1024] t-major
    unsigned short* __restrict__ H0lo,
    unsigned* __restrict__ bar,
    const float* __restrict__ Wx1,
    const float* __restrict__ Wh1,
    unsigned short* __restrict__ BThi,
    unsigned short* __restrict__ BTlo) {
  __shared__ float red[12288];                 // 48 KB
  const int tid = threadIdx.x;
  const int wg = blockIdx.x;

  if (wg >= 32) {
    // ---------- helper: static-striped Wx1/Wh1 transpose+split into BT, then exit ----------
    float* tile = red;                          // [32][33]
    const int ty = tid >> 5, tx = tid & 31;     // ty in [0,16)
    for (int tix = wg - 32; tix < 6144; tix += 224) {
      const int job = tix >= 3072;
      const int tt = job ? tix - 3072 : tix;
      const int c0 = (tt % 96) * 32, r0 = (tt / 96) * 32;
      const float* W = job ? Wh1 : Wx1;
      unsigned short* Dhi = BThi + (job ? (size_t)H3 * H_ : 0);
      unsigned short* Dlo = BTlo + (job ? (size_t)H3 * H_ : 0);
      __syncthreads();
      tile[ty * 33 + tx]        = W[(size_t)(r0 + ty) * H3 + c0 + tx];
      tile[(ty + 16) * 33 + tx] = W[(size_t)(r0 + ty + 16) * H3 + c0 + tx];
      __syncthreads();
      #pragma unroll
      for (int s = 0; s < 2; ++s) {
        const int i = ty + s * 16;
        unsigned short h, l;
        split_f32(tile[tx * 33 + i], h, l);
        Dhi[(size_t)(c0 + i) * H_ + r0 + tx] = h;
        Dlo[(size_t)(c0 + i) * H_ + r0 + tx] = l;
      }
    }
    return;
  }

  // ---------- participant WG `rank` owns h-cols [32*rank, 32*rank+32) ----------
  const int rank = wg;
  const int wv = tid >> 6, l = tid & 63;
  const int b  = tid >> 5, jj = tid & 31;
  const int col = rank * 32 + jj;

  bf16x8 breg[6][4];
  #pragma unroll
  for (int nf = 0; nf < 6; ++nf) {
    const int g = nf >> 1, h2 = nf & 1;
    const int bcol = g * 1024 + rank * 32 + h2 * 16 + (l & 15);
    #pragma unroll
    for (int kf = 0; kf < 4; ++kf)
      breg[nf][kf] = *(const bf16x8*)(WhTb + (size_t)bcol * 1024 + wv * 128 + kf * 32 + ((l >> 4) << 3));
  }
  const float bhr = bh0[col], bhz = bh0[1024 + col], bhn = bh0[2048 + col];

  float xr, xz, xn;
  {
    const size_t g0 = (size_t)(0 * 16 + b) * H3;
    xr = GX0[g0 + col]; xz = GX0[g0 + 1024 + col]; xn = GX0[g0 + 2048 + col];
  }
  float hprev = 0.f;

  for (int t = 0; t < T_; ++t) {
    bf16x8 ahi[4], alo[4];
    if (t == 0) {
      #pragma unroll
      for (int kf = 0; kf < 4; ++kf) {
        ahi[kf] = (bf16x8){0, 0, 0, 0, 0, 0, 0, 0};
        alo[kf] = (bf16x8){0, 0, 0, 0, 0, 0, 0, 0};
      }
    } else {
      const unsigned* tp = &bar[(unsigned)((4 * wv + (l & 3)) * 32 + rank) * 32];
      int guard = 0;
      for (;;) {
        const unsigned v = AGENT_LD(tp);
        if (__all(v >= (unsigned)t)) break;
        if (++guard > 10000000) break;
      }
      const size_t aoff = (size_t)(t - 1) * 32768 + ((l & 15) * 2048)
                          + ((wv * 128 + ((l >> 4) << 3)) << 1);
      const char* abh = (const char*)H0hi + aoff;
      const char* abl = (const char*)H0lo + aoff;
      #pragma unroll
      for (int kf = 0; kf < 4; ++kf) {
        asm volatile("global_load_dwordx4 %0, %1, off sc0 sc1" : "=v"(ahi[kf]) : "v"(abh + kf * 64));
        asm volatile("global_load_dwordx4 %0, %1, off sc0 sc1" : "=v"(alo[kf]) : "v"(abl + kf * 64));
      }
      asm volatile("s_waitcnt vmcnt(0)" ::: "memory");
      __builtin_amdgcn_sched_barrier(0);       // RULE #18
    }

    #pragma unroll
    for (int nf = 0; nf < 6; ++nf) {
      f32x4 a4 = (f32x4){0.f, 0.f, 0.f, 0.f};
      #pragma unroll
      for (int kf = 0; kf < 4; ++kf) {
        a4 = __builtin_amdgcn_mfma_f32_16x16x32_bf16(ahi[kf], breg[nf][kf], a4, 0, 0, 0);
        a4 = __builtin_amdgcn_mfma_f32_16x16x32_bf16(alo[kf], breg[nf][kf], a4, 0, 0, 0);
      }
      *(f32x4*)&red[(((wv * 6 + nf) << 6) + l) << 2] = a4;
    }
    __syncthreads();

    const int h2 = jj >> 4, f = jj & 15;
    const int lp = ((b >> 2) << 4) + f, ii = b & 3;
    float p3[3];
    #pragma unroll
    for (int g = 0; g < 3; ++g) {
      const int nf = g * 2 + h2;
      float s = 0.f;
      #pragma unroll
      for (int w8 = 0; w8 < 8; ++w8)
        s += red[((((w8 * 6 + nf) << 6) + lp) << 2) + ii];
      p3[g] = s;
    }
    const float r = 1.f / (1.f + expf(-(xr + p3[0] + bhr)));
    const float z = 1.f / (1.f + expf(-(xz + p3[1] + bhz)));
    const float n = tanhf(xn + r * (p3[2] + bhn));
    const float hnew = (1.f - z) * n + z * hprev;
    hprev = hnew;
    unsigned short hh, hl;
    split_f32(hnew, hh, hl);

    {
      const unsigned tmp = (unsigned)hh | ((unsigned)hl << 16);
      const unsigned nb = __shfl_xor(tmp, 1);
      if ((jj & 1) == 0) {
        const unsigned hw = (tmp & 0xffffu) | ((nb & 0xffffu) << 16);
        const unsigned lw = (tmp >> 16) | (nb & 0xffff0000u);
        const size_t u32i = (((size_t)(t * 16 + b) << 10) + col) >> 1;
        AGENT_ST((unsigned*)H0hi + u32i, hw);
        AGENT_ST((unsigned*)H0lo + u32i, lw);
      }
    }

    if (t + 1 < T_) {
      __syncthreads();                         // vmcnt(0) drain: h stores at LLC
      if (tid < 32) AGENT_ST(&bar[(unsigned)(rank * 32 + tid) * 32], (unsigned)(t + 1));
      {
        const size_t g0 = (size_t)((t + 1) * 16 + b) * H3;
        xr = GX0[g0 + col]; xz = GX0[g0 + 1024 + col]; xn = GX0[g0 + 2048 + col];
      }
    }
  }
}

// ---------------- layer-1 elementwise: writes H1 as fp16 (single plane) ----------------
__global__ __launch_bounds__(256) void k_gru1(const float* __restrict__ G1,
                                              const unsigned short* __restrict__ H0hi,
                                              const unsigned short* __restrict__ H0lo,
                                              _Float16* __restrict__ H1f, int row0) {
  const int lrow = blockIdx.x;
  const size_t row = (size_t)row0 + lrow;
  const float* g = G1 + (size_t)lrow * 6144;
  for (int j = threadIdx.x; j < H_; j += 256) {
    const float xr = g[j], xz = g[1024 + j], xn = g[2048 + j];
    const float hr = g[3072 + j], hz = g[4096 + j], hn = g[5120 + j];
    const size_t idx = (row << 10) + j;
    const float h = join_bf(H0hi[idx], H0lo[idx]);
    const float r = 1.f / (1.f + expf(-(xr + hr)));
    const float z = 1.f / (1.f + expf(-(xz + hz)));
    const float n = tanhf(xn + r * hn);
    H1f[idx] = (_Float16)((1.f - z) * n + z * h);
  }
}

// ---------------- final hidden: out[2][B][H] ----------------
__global__ __launch_bounds__(256) void k_hidden(const unsigned short* __restrict__ H0hi,
                                                const unsigned short* __restrict__ H0lo,
                                                const _Float16* __restrict__ H1f,
                                                float* __restrict__ out) {
  const int i = blockIdx.x * 256 + threadIdx.x;
  const int l = i >> 14;
  const int b = (i >> 10) & 15;
  const int j = i & 1023;
  const size_t idx = ((size_t)(255 * 16 + b) << 10) + j;   // t = T-1, t-major
  out[i] = l ? (float)H1f[idx] : join_bf(H0hi[idx], H0lo[idx]);
}

extern "C" void kernel_launch(void* const* d_in, const int* in_sizes, int n_in,
                              void* d_out, int out_size, void* d_ws, size_t ws_size,
                              hipStream_t stream) {
  const int*   x   = (const int*)d_in[0];
  const float* emb = (const float*)d_in[1];
  const float* Wx0 = (const float*)d_in[2];
  const float* Wh0 = (const float*)d_in[3];
  const float* bx0 = (const float*)d_in[4];
  const float* bh0 = (const float*)d_in[5];
  const float* Wx1 = (const float*)d_in[6];
  const float* Wh1 = (const float*)d_in[7];
  const float* bx1 = (const float*)d_in[8];
  const float* bh1 = (const float*)d_in[9];
  const float* fcW = (const float*)d_in[10];
  const float* fcb = (const float*)d_in[11];
  float* out = (float*)d_out;

  char* ws = (char*)d_ws;
  const size_t MB = 1024 * 1024;
  // persistent hidden states (t-major rows)
  unsigned short* H0hi = (unsigned short*)(ws + 0);        // 8 MB [4096][1024]
  unsigned short* H0lo = (unsigned short*)(ws + 8 * MB);   // 8 MB
  _Float16*       H1f  = (_Float16*)(ws + 16 * MB);        // 8 MB [4096][1024] fp16
  char* S = ws + 32 * MB;
  // phase A/B
  unsigned short* WhTb  = (unsigned short*)(S);            // 6 MB
  float*          GX0   = (float*)(S + 8 * MB);            // 48 MB (t-major)
  unsigned short* EmbHi = (unsigned short*)(S + 56 * MB);  // 4 MB (dead after GX0 gemm)
  unsigned short* EmbLo = (unsigned short*)(S + 60 * MB);  // 4 MB
  unsigned short* Wx0Thi= (unsigned short*)(S + 64 * MB);  // 3 MB
  unsigned short* Wx0Tlo= (unsigned short*)(S + 67 * MB);  // 3 MB
  // written by helper WGs during k_recur3 (over the corpses above):
  unsigned short* BThi  = (unsigned short*)(S + 56 * MB);  // 12 MB [6144][1024] (Wx1T|Wh1T)
  unsigned short* BTlo  = (unsigned short*)(S + 68 * MB);  // 12 MB
  unsigned*       bar   = (unsigned*)(S + 80 * MB);        // 128 KB tag matrix
  float*          b1cat = (float*)(S + 80 * MB + 131072);  // 24 KB
  // phase C (GX0 corpse)
  float* G1 = (float*)(S + 8 * MB);                        // 48 MB [2048][6144]
  // phase D
  _Float16* fcTf = (_Float16*)(S);                         // 31.25 MB [16000][1024] fp16

  // ---- phase A: embeddings (split, t-major), Wh0->bf16, Wx0 split-T, GX0 via MFMA ----
  k_embed_split<<<dim3(B_ * T_), dim3(128), 0, stream>>>(x, emb, EmbHi, EmbLo);
  k_transpose_b16<<<dim3(H3 / 32, H_ / 32), dim3(256), 0, stream>>>(Wh0, WhTb);
  k_transpose_split<<<dim3(H3 / 32, E_ / 32), dim3(256), 0, stream>>>(Wx0, H3, Wx0Thi, Wx0Tlo, E_);
  k_gemm_mfma<<<dim3(32 * 24), dim3(256), 0, stream>>>(
      EmbHi, EmbLo, Wx0Thi, Wx0Tlo, bx0, GX0, 32, 24, E_, H3, 0);
  k_catbias<<<dim3(12), dim3(512), 0, stream>>>(bx1, bh1, b1cat);

  // ---- phase B: recurrence (WGs 0-31) + Wx1/Wh1 transposes (WGs 32-255) ----
  hipMemsetAsync(bar, 0, 131072, stream);
  {
    void* args[] = {(void*)&WhTb, (void*)&GX0, (void*)&bh0, (void*)&H0hi, (void*)&H0lo,
                    (void*)&bar, (void*)&Wx1, (void*)&Wh1, (void*)&BThi, (void*)&BTlo};
    hipLaunchCooperativeKernel((const void*)k_recur3, dim3(256), dim3(512), args, 0, stream);
  }

  // ---- phase C: layer 1, one merged GEMM per chunk (N = 6144) ----
  for (int chunk = 0; chunk < 2; ++chunk) {
    const unsigned short* Ah = H0hi + (size_t)chunk * 2048 * H_;
    const unsigned short* Al = H0lo + (size_t)chunk * 2048 * H_;
    k_gemm_mfma<<<dim3(16 * 48), dim3(256), 0, stream>>>(
        Ah, Al, BThi, BTlo, b1cat, G1, 16, 48, H_, 6144, 0);
    k_gru1<<<dim3(2048), dim3(256), 0, stream>>>(G1, H0hi, H0lo, H1f, chunk * 2048);
  }

  // ---- phase D: FC via single-pass fp16 MFMA, 2 N-chunks of 16000 ----
  for (int chunk = 0; chunk < 2; ++chunk) {
    const float* Wc = fcW + (size_t)chunk * 16000;
    k_transpose_f16<<<dim3(16000 / 32, H_ / 32), dim3(256), 0, stream>>>(Wc, V_, fcTf, H_);
    k_gemm_f16<<<dim3(32 * 125), dim3(256), 0, stream>>>(
        H1f, fcTf, fcb + (size_t)chunk * 16000,
        out + (size_t)chunk * 16000, 32, 125, H_, V_, 1);
  }

  // ---- final hidden ----
  k_hidden<<<dim3(32768 / 256), dim3(256), 0, stream>>>(H0hi, H0lo, H1f,
                                                        out + (size_t)B_ * T_ * V_);
}

// Round 16
// 1403.583 us; speedup vs baseline: 1.5504x; 1.2765x over previous
//
#include <hip/hip_runtime.h>
#include <hip/hip_bf16.h>

#define V_  32000
#define E_  512
#define H_  1024
#define B_  16
#define T_  256
#define H3  3072

#define AGENT_LD(p)    __hip_atomic_load((p),  __ATOMIC_RELAXED, __HIP_MEMORY_SCOPE_AGENT)
#define AGENT_ST(p, v) __hip_atomic_store((p), (v), __ATOMIC_RELAXED, __HIP_MEMORY_SCOPE_AGENT)

typedef __attribute__((ext_vector_type(8))) short bf16x8;
typedef __attribute__((ext_vector_type(8))) _Float16 f16x8;
typedef __attribute__((ext_vector_type(4))) float f32x4;

#define GLDS16(gp, lp) __builtin_amdgcn_global_load_lds( \
    (const __attribute__((address_space(1))) unsigned int*)(gp), \
    (__attribute__((address_space(3))) unsigned int*)(lp), 16, 0, 0)

__device__ __forceinline__ void split_f32(float v, unsigned short& hi, unsigned short& lo) {
  const __hip_bfloat16 hb = __float2bfloat16(v);
  hi = *(const unsigned short*)&hb;
  const __hip_bfloat16 lb = __float2bfloat16(v - __bfloat162float(hb));
  lo = *(const unsigned short*)&lb;
}

// ---------------- embedding gather + hi/lo split (writes t-major rows) ----------------
__global__ __launch_bounds__(128) void k_embed_split(const int* __restrict__ x,
                                                     const float* __restrict__ emb,
                                                     unsigned short* __restrict__ hi,
                                                     unsigned short* __restrict__ lo) {
  const int rin = blockIdx.x;                  // b*T + t (x layout)
  const int b = rin >> 8, t = rin & 255;
  const int orow = t * 16 + b;                 // t-major
  const int idx = x[rin];
  const float4 v = ((const float4*)(emb + (size_t)idx * E_))[threadIdx.x];
  const float f[4] = {v.x, v.y, v.z, v.w};
  unsigned short hh[4], ll[4];
  #pragma unroll
  for (int k = 0; k < 4; ++k) split_f32(f[k], hh[k], ll[k]);
  ushort4 h4; h4.x = hh[0]; h4.y = hh[1]; h4.z = hh[2]; h4.w = hh[3];
  ushort4 l4; l4.x = ll[0]; l4.y = ll[1]; l4.z = ll[2]; l4.w = ll[3];
  ((ushort4*)(hi + (size_t)orow * E_))[threadIdx.x] = h4;
  ((ushort4*)(lo + (size_t)orow * E_))[threadIdx.x] = l4;
}

// ---------------- transpose + hi/lo split (bf16 pair planes) ----------------
__global__ __launch_bounds__(256) void k_transpose_split(const float* __restrict__ W, int ldw,
                                                         unsigned short* __restrict__ WThi,
                                                         unsigned short* __restrict__ WTlo,
                                                         int R) {
  __shared__ float tile[32][33];
  const int c0 = blockIdx.x * 32, r0 = blockIdx.y * 32;
  const int tx = threadIdx.x & 31, ty = threadIdx.x >> 5;
  #pragma unroll
  for (int i = ty; i < 32; i += 8)
    tile[i][tx] = W[(size_t)(r0 + i) * ldw + c0 + tx];
  __syncthreads();
  #pragma unroll
  for (int i = ty; i < 32; i += 8) {
    unsigned short h, l;
    split_f32(tile[tx][i], h, l);
    WThi[(size_t)(c0 + i) * R + r0 + tx] = h;
    WTlo[(size_t)(c0 + i) * R + r0 + tx] = l;
  }
}

// ---------------- transpose to fp16: W [R][ldw] f32 -> WT [C][R] fp16 ----------------
__global__ __launch_bounds__(256) void k_transpose_f16(const float* __restrict__ W, int ldw,
                                                       _Float16* __restrict__ WT, int R) {
  __shared__ float tile[32][33];
  const int c0 = blockIdx.x * 32, r0 = blockIdx.y * 32;
  const int tx = threadIdx.x & 31, ty = threadIdx.x >> 5;
  #pragma unroll
  for (int i = ty; i < 32; i += 8)
    tile[i][tx] = W[(size_t)(r0 + i) * ldw + c0 + tx];
  __syncthreads();
  #pragma unroll
  for (int i = ty; i < 32; i += 8)
    WT[(size_t)(c0 + i) * R + r0 + tx] = (_Float16)tile[tx][i];
}

// ---------------- bias concat ----------------
__global__ __launch_bounds__(512) void k_catbias(const float* __restrict__ a,
                                                 const float* __restrict__ b,
                                                 float* __restrict__ o) {
  const int i = blockIdx.x * 512 + threadIdx.x;
  o[i] = (i < H3) ? a[i] : b[i - H3];
}

// ---------------- split-bf16 MFMA GEMM (proven; used for GX0) ----------------
__global__ __launch_bounds__(256, 2) void k_gemm_mfma(
    const unsigned short* __restrict__ Ahi, const unsigned short* __restrict__ Alo,
    const unsigned short* __restrict__ BThi, const unsigned short* __restrict__ BTlo,
    const float* __restrict__ bias, float* __restrict__ C,
    int MT, int NT, int K, int ldc, int remap) {
  __shared__ unsigned short sAhi[128 * 64], sAlo[128 * 64];
  __shared__ unsigned short sBhi[128 * 64], sBlo[128 * 64];

  const int bid = blockIdx.x;
  const int GROUPM = 8;
  const int group = bid / (GROUPM * NT);
  const int first = group * GROUPM;
  const int gsm = (MT - first < GROUPM) ? (MT - first) : GROUPM;
  const int rem = bid % (GROUPM * NT);
  const int pm = first + rem % gsm;
  const int pn = rem / gsm;
  const int bm = pm * 128, bn = pn * 128;

  const int tid = threadIdx.x;
  const int wv = tid >> 6, l = tid & 63;
  const int wr = wv >> 1, wc = wv & 1;
  const int frow = l & 15;
  const int ksl  = l >> 4;

  f32x4 acc[4][4];
  #pragma unroll
  for (int a = 0; a < 4; ++a)
    #pragma unroll
    for (int b = 0; b < 4; ++b) acc[a][b] = (f32x4){0.f, 0.f, 0.f, 0.f};

  for (int k0 = 0; k0 < K; k0 += 64) {
    __syncthreads();
    #pragma unroll
    for (int p = 0; p < 4; ++p) {
      const int obase = ((p << 2) + wv) << 10;
      const int row = ((obase >> 7)) + (l >> 3);
      const int slot = l & 7;
      const int gcol = k0 + ((slot ^ (row & 7)) << 3);
      const size_t ga = (size_t)(bm + row) * K + gcol;
      const size_t gb = (size_t)(bn + row) * K + gcol;
      GLDS16(Ahi + ga, (char*)sAhi + obase);
      GLDS16(Alo + ga, (char*)sAlo + obase);
      GLDS16(BThi + gb, (char*)sBhi + obase);
      GLDS16(BTlo + gb, (char*)sBlo + obase);
    }
    __syncthreads();
    #pragma unroll
    for (int kk = 0; kk < 2; ++kk) {
      bf16x8 ah[4], al[4], bh[4], bl[4];
      #pragma unroll
      for (int f = 0; f < 4; ++f) {
        const int ar = wr * 64 + f * 16 + frow;
        const int aoff = ar * 128 + ((((kk << 2) + ksl) ^ (ar & 7)) << 4);
        ah[f] = *(const bf16x8*)((const char*)sAhi + aoff);
        al[f] = *(const bf16x8*)((const char*)sAlo + aoff);
        const int br_ = wc * 64 + f * 16 + frow;
        const int boff = br_ * 128 + ((((kk << 2) + ksl) ^ (br_ & 7)) << 4);
        bh[f] = *(const bf16x8*)((const char*)sBhi + boff);
        bl[f] = *(const bf16x8*)((const char*)sBlo + boff);
      }
      #pragma unroll
      for (int fm = 0; fm < 4; ++fm)
        #pragma unroll
        for (int fn = 0; fn < 4; ++fn) {
          acc[fm][fn] = __builtin_amdgcn_mfma_f32_16x16x32_bf16(ah[fm], bh[fn], acc[fm][fn], 0, 0, 0);
          acc[fm][fn] = __builtin_amdgcn_mfma_f32_16x16x32_bf16(ah[fm], bl[fn], acc[fm][fn], 0, 0, 0);
          acc[fm][fn] = __builtin_amdgcn_mfma_f32_16x16x32_bf16(al[fm], bh[fn], acc[fm][fn], 0, 0, 0);
        }
    }
  }

  const int crow0 = bm + wr * 64 + (l >> 4) * 4;
  const int ccol0 = bn + wc * 64 + (l & 15);
  #pragma unroll
  for (int fn = 0; fn < 4; ++fn) {
    const int col = ccol0 + fn * 16;
    const float bv = bias[col];
    #pragma unroll
    for (int fm = 0; fm < 4; ++fm) {
      const int r0 = crow0 + fm * 16;
      #pragma unroll
      for (int i = 0; i < 4; ++i) {
        const int rr = r0 + i;
        const int orow = remap ? ((rr & 15) * T_ + (rr >> 4)) : rr;
        C[(size_t)orow * ldc + col] = acc[fm][fn][i] + bv;
      }
    }
  }
}

// ---------------- single-pass fp16 MFMA GEMM (layer-1 + FC) ----------------
__global__ __launch_bounds__(256, 4) void k_gemm_f16(
    const _Float16* __restrict__ A, const _Float16* __restrict__ BT,
    const float* __restrict__ bias, float* __restrict__ C,
    int MT, int NT, int K, int ldc, int remap) {
  __shared__ _Float16 sA[128 * 64], sB[128 * 64];

  const int bid = blockIdx.x;
  const int GROUPM = 8;
  const int group = bid / (GROUPM * NT);
  const int first = group * GROUPM;
  const int gsm = (MT - first < GROUPM) ? (MT - first) : GROUPM;
  const int rem = bid % (GROUPM * NT);
  const int pm = first + rem % gsm;
  const int pn = rem / gsm;
  const int bm = pm * 128, bn = pn * 128;

  const int tid = threadIdx.x;
  const int wv = tid >> 6, l = tid & 63;
  const int wr = wv >> 1, wc = wv & 1;
  const int frow = l & 15;
  const int ksl  = l >> 4;

  f32x4 acc[4][4];
  #pragma unroll
  for (int a = 0; a < 4; ++a)
    #pragma unroll
    for (int b = 0; b < 4; ++b) acc[a][b] = (f32x4){0.f, 0.f, 0.f, 0.f};

  for (int k0 = 0; k0 < K; k0 += 64) {
    __syncthreads();
    #pragma unroll
    for (int p = 0; p < 4; ++p) {
      const int obase = ((p << 2) + wv) << 10;
      const int row = ((obase >> 7)) + (l >> 3);
      const int slot = l & 7;
      const int gcol = k0 + ((slot ^ (row & 7)) << 3);
      GLDS16(A + (size_t)(bm + row) * K + gcol, (char*)sA + obase);
      GLDS16(BT + (size_t)(bn + row) * K + gcol, (char*)sB + obase);
    }
    __syncthreads();
    #pragma unroll
    for (int kk = 0; kk < 2; ++kk) {
      f16x8 a[4], b[4];
      #pragma unroll
      for (int f = 0; f < 4; ++f) {
        const int ar = wr * 64 + f * 16 + frow;
        a[f] = *(const f16x8*)((const char*)sA + ar * 128 + ((((kk << 2) + ksl) ^ (ar & 7)) << 4));
        const int br_ = wc * 64 + f * 16 + frow;
        b[f] = *(const f16x8*)((const char*)sB + br_ * 128 + ((((kk << 2) + ksl) ^ (br_ & 7)) << 4));
      }
      #pragma unroll
      for (int fm = 0; fm < 4; ++fm)
        #pragma unroll
        for (int fn = 0; fn < 4; ++fn)
          acc[fm][fn] = __builtin_amdgcn_mfma_f32_16x16x32_f16(a[fm], b[fn], acc[fm][fn], 0, 0, 0);
    }
  }

  const int crow0 = bm + wr * 64 + (l >> 4) * 4;
  const int ccol0 = bn + wc * 64 + (l & 15);
  #pragma unroll
  for (int fn = 0; fn < 4; ++fn) {
    const int col = ccol0 + fn * 16;
    const float bv = bias[col];
    #pragma unroll
    for (int fm = 0; fm < 4; ++fm) {
      const int r0 = crow0 + fm * 16;
      #pragma unroll
      for (int i = 0; i < 4; ++i) {
        const int rr = r0 + i;
        const int orow = remap ? ((rr & 15) * T_ + (rr >> 4)) : rr;
        C[(size_t)orow * ldc + col] = acc[fm][fn][i] + bv;
      }
    }
  }
}

// ---------------- layer-0 recurrence: fp16 single-plane h, fp16 Wh B-frags ----------------
// Structure identical to round-13 proven kernel: 32 MFMA WGs + per-wave dataflow tags,
// 224 helper WGs transpose Wx1/Wh1 to single fp16 plane. RULE #18 fence kept.
__global__ __launch_bounds__(512, 1) void k_recur3(
    const _Float16* __restrict__ WhTf,         // [3072][1024] fp16
    const float* __restrict__ GX0,             // [4096][3072] f32, t-major rows
    const float* __restrict__ bh0,
    _Float16* __restrict__ H0f,                // [4096][1024] fp16, t-major
    float* __restrict__ H0last,                // [16][1024] f32 (t = T-1)
    unsigned* __restrict__ bar,
    const float* __restrict__ Wx1,
    const float* __restrict__ Wh1,
    _Float16* __restrict__ BTf) {              // [6144][1024] fp16 (Wx1T|Wh1T)
  __shared__ float red[12288];                 // 48 KB
  const int tid = threadIdx.x;
  const int wg = blockIdx.x;

  if (wg >= 32) {
    // ---------- helper: static-striped Wx1/Wh1 transpose to fp16, then exit ----------
    float* tile = red;                          // [32][33]
    const int ty = tid >> 5, tx = tid & 31;     // ty in [0,16)
    for (int tix = wg - 32; tix < 6144; tix += 224) {
      const int job = tix >= 3072;
      const int tt = job ? tix - 3072 : tix;
      const int c0 = (tt % 96) * 32, r0 = (tt / 96) * 32;
      const float* W = job ? Wh1 : Wx1;
      _Float16* D = BTf + (job ? (size_t)H3 * H_ : 0);
      __syncthreads();
      tile[ty * 33 + tx]        = W[(size_t)(r0 + ty) * H3 + c0 + tx];
      tile[(ty + 16) * 33 + tx] = W[(size_t)(r0 + ty + 16) * H3 + c0 + tx];
      __syncthreads();
      #pragma unroll
      for (int s = 0; s < 2; ++s) {
        const int i = ty + s * 16;
        D[(size_t)(c0 + i) * H_ + r0 + tx] = (_Float16)tile[tx * 33 + i];
      }
    }
    return;
  }

  // ---------- participant WG `rank` owns h-cols [32*rank, 32*rank+32) ----------
  const int rank = wg;
  const int wv = tid >> 6, l = tid & 63;
  const int b  = tid >> 5, jj = tid & 31;
  const int col = rank * 32 + jj;

  // one-time Wh B-frags into VGPRs (fp16, same frag layout as proven k_gemm_f16)
  f16x8 breg[6][4];
  #pragma unroll
  for (int nf = 0; nf < 6; ++nf) {
    const int g = nf >> 1, h2 = nf & 1;
    const int bcol = g * 1024 + rank * 32 + h2 * 16 + (l & 15);
    #pragma unroll
    for (int kf = 0; kf < 4; ++kf)
      breg[nf][kf] = *(const f16x8*)(WhTf + (size_t)bcol * 1024 + wv * 128 + kf * 32 + ((l >> 4) << 3));
  }
  const float bhr = bh0[col], bhz = bh0[1024 + col], bhn = bh0[2048 + col];

  float xr, xz, xn;
  {
    const size_t g0 = (size_t)(0 * 16 + b) * H3;
    xr = GX0[g0 + col]; xz = GX0[g0 + 1024 + col]; xn = GX0[g0 + 2048 + col];
  }
  float hprev = 0.f;

  for (int t = 0; t < T_; ++t) {
    f16x8 af[4];
    if (t == 0) {
      #pragma unroll
      for (int kf = 0; kf < 4; ++kf)
        af[kf] = (f16x8){0, 0, 0, 0, 0, 0, 0, 0};
    } else {
      // ---- per-wave dataflow wait: this wave's 4 producers must have published t ----
      const unsigned* tp = &bar[(unsigned)((4 * wv + (l & 3)) * 32 + rank) * 32];
      int guard = 0;
      for (;;) {
        const unsigned v = AGENT_LD(tp);
        if (__all(v >= (unsigned)t)) break;
        if (++guard > 10000000) break;         // hang guard -> degrade to wrong answer
      }
      // ---- A-frags from H0f plane (t-1 block is contiguous 32KB) ----
      const char* ab = (const char*)H0f + (size_t)(t - 1) * 32768 + ((l & 15) * 2048)
                       + ((wv * 128 + ((l >> 4) << 3)) << 1);
      #pragma unroll
      for (int kf = 0; kf < 4; ++kf)
        asm volatile("global_load_dwordx4 %0, %1, off sc0 sc1" : "=v"(af[kf]) : "v"(ab + kf * 64));
      asm volatile("s_waitcnt vmcnt(0)" ::: "memory");
      __builtin_amdgcn_sched_barrier(0);       // RULE #18: MFMA must not hoist past waitcnt
    }

    #pragma unroll
    for (int nf = 0; nf < 6; ++nf) {
      f32x4 a4 = (f32x4){0.f, 0.f, 0.f, 0.f};
      #pragma unroll
      for (int kf = 0; kf < 4; ++kf)
        a4 = __builtin_amdgcn_mfma_f32_16x16x32_f16(af[kf], breg[nf][kf], a4, 0, 0, 0);
      *(f32x4*)&red[(((wv * 6 + nf) << 6) + l) << 2] = a4;
    }
    __syncthreads();   // all 8 waves passed tag-wait t (RAW gate; WAR vacuous in t-major)

    // ---- reduce 8 wave-partials + gates; thread = (b, jj) ----
    const int h2 = jj >> 4, f = jj & 15;
    const int lp = ((b >> 2) << 4) + f, ii = b & 3;
    float p3[3];
    #pragma unroll
    for (int g = 0; g < 3; ++g) {
      const int nf = g * 2 + h2;
      float s = 0.f;
      #pragma unroll
      for (int w8 = 0; w8 < 8; ++w8)
        s += red[((((w8 * 6 + nf) << 6) + lp) << 2) + ii];
      p3[g] = s;
    }
    const float r = 1.f / (1.f + expf(-(xr + p3[0] + bhr)));
    const float z = 1.f / (1.f + expf(-(xz + p3[1] + bhz)));
    const float n = tanhf(xn + r * (p3[2] + bhn));
    const float hnew = (1.f - z) * n + z * hprev;
    hprev = hnew;

    // ---- publish h to H0f (packed fp16 col-pairs, AGENT_ST u32) ----
    {
      const _Float16 hf = (_Float16)hnew;
      const unsigned tmp = (unsigned)*(const unsigned short*)&hf;
      const unsigned nb = __shfl_xor(tmp, 1);
      if ((jj & 1) == 0) {
        const unsigned w = (tmp & 0xffffu) | (nb << 16);
        const size_t u32i = (((size_t)(t * 16 + b) << 10) + col) >> 1;
        AGENT_ST((unsigned*)H0f + u32i, w);
      }
    }
    if (t == T_ - 1) H0last[(b << 10) + col] = hnew;   // f32 final h0

    if (t + 1 < T_) {
      __syncthreads();                         // vmcnt(0) drain: h stores at LLC
      if (tid < 32) AGENT_ST(&bar[(unsigned)(rank * 32 + tid) * 32], (unsigned)(t + 1));
      {                                        // GX0 prefetch for t+1 (off critical path)
        const size_t g0 = (size_t)((t + 1) * 16 + b) * H3;
        xr = GX0[g0 + col]; xz = GX0[g0 + 1024 + col]; xn = GX0[g0 + 2048 + col];
      }
    }
  }
}

// ---------------- layer-1 elementwise: fp16 h0 in, fp16 H1 out (+f32 final block) ----------------
__global__ __launch_bounds__(256) void k_gru1(const float* __restrict__ G1,
                                              const _Float16* __restrict__ H0f,
                                              _Float16* __restrict__ H1f,
                                              float* __restrict__ H1last, int row0) {
  const int lrow = blockIdx.x;
  const int row = row0 + lrow;                 // t-major
  const float* g = G1 + (size_t)lrow * 6144;
  for (int j = threadIdx.x; j < H_; j += 256) {
    const float xr = g[j], xz = g[1024 + j], xn = g[2048 + j];
    const float hr = g[3072 + j], hz = g[4096 + j], hn = g[5120 + j];
    const size_t idx = ((size_t)row << 10) + j;
    const float h = (float)H0f[idx];
    const float r = 1.f / (1.f + expf(-(xr + hr)));
    const float z = 1.f / (1.f + expf(-(xz + hz)));
    const float n = tanhf(xn + r * hn);
    const float hnew = (1.f - z) * n + z * h;
    H1f[idx] = (_Float16)hnew;
    if (row >= 4080) H1last[((row - 4080) << 10) + j] = hnew;  // f32 final h1
  }
}

// ---------------- final hidden: out[2][B][H] from f32 last-step buffers ----------------
__global__ __launch_bounds__(256) void k_hidden(const float* __restrict__ H0last,
                                                const float* __restrict__ H1last,
                                                float* __restrict__ out) {
  const int i = blockIdx.x * 256 + threadIdx.x;
  const int l = i >> 14;
  const int bj = i & 16383;
  out[i] = l ? H1last[bj] : H0last[bj];
}

extern "C" void kernel_launch(void* const* d_in, const int* in_sizes, int n_in,
                              void* d_out, int out_size, void* d_ws, size_t ws_size,
                              hipStream_t stream) {
  const int*   x   = (const int*)d_in[0];
  const float* emb = (const float*)d_in[1];
  const float* Wx0 = (const float*)d_in[2];
  const float* Wh0 = (const float*)d_in[3];
  const float* bx0 = (const float*)d_in[4];
  const float* bh0 = (const float*)d_in[5];
  const float* Wx1 = (const float*)d_in[6];
  const float* Wh1 = (const float*)d_in[7];
  const float* bx1 = (const float*)d_in[8];
  const float* bh1 = (const float*)d_in[9];
  const float* fcW = (const float*)d_in[10];
  const float* fcb = (const float*)d_in[11];
  float* out = (float*)d_out;

  char* ws = (char*)d_ws;
  const size_t MB = 1024 * 1024;
  // persistent hidden states (t-major rows)
  _Float16* H0f    = (_Float16*)(ws + 0);                  // 8 MB [4096][1024] fp16
  _Float16* H1f    = (_Float16*)(ws + 8 * MB);             // 8 MB
  float*    H0last = (float*)(ws + 16 * MB);               // 64 KB f32 [16][1024]
  float*    H1last = (float*)(ws + 16 * MB + 65536);       // 64 KB
  char* S = ws + 32 * MB;
  // phase A/B
  _Float16*       WhTf  = (_Float16*)(S);                  // 6 MB [3072][1024] fp16
  float*          GX0   = (float*)(S + 8 * MB);            // 48 MB (t-major)
  unsigned short* EmbHi = (unsigned short*)(S + 56 * MB);  // 4 MB (dead after GX0 gemm)
  unsigned short* EmbLo = (unsigned short*)(S + 60 * MB);  // 4 MB
  unsigned short* Wx0Thi= (unsigned short*)(S + 64 * MB);  // 3 MB
  unsigned short* Wx0Tlo= (unsigned short*)(S + 67 * MB);  // 3 MB
  // written by helper WGs during k_recur3 (over the corpses above):
  _Float16*       BTf   = (_Float16*)(S + 56 * MB);        // 12 MB [6144][1024] fp16
  unsigned*       bar   = (unsigned*)(S + 80 * MB);        // 128 KB tag matrix
  float*          b1cat = (float*)(S + 80 * MB + 131072);  // 24 KB
  // phase C (GX0 corpse)
  float* G1 = (float*)(S + 8 * MB);                        // 48 MB [2048][6144]
  // phase D
  _Float16* fcTf = (_Float16*)(S);                         // 31.25 MB [16000][1024] fp16

  // ---- phase A: embeddings (split, t-major), Wh0->fp16 T, Wx0 split-T, GX0 via MFMA ----
  k_embed_split<<<dim3(B_ * T_), dim3(128), 0, stream>>>(x, emb, EmbHi, EmbLo);
  k_transpose_f16<<<dim3(H3 / 32, H_ / 32), dim3(256), 0, stream>>>(Wh0, H3, WhTf, H_);
  k_transpose_split<<<dim3(H3 / 32, E_ / 32), dim3(256), 0, stream>>>(Wx0, H3, Wx0Thi, Wx0Tlo, E_);
  k_gemm_mfma<<<dim3(32 * 24), dim3(256), 0, stream>>>(
      EmbHi, EmbLo, Wx0Thi, Wx0Tlo, bx0, GX0, 32, 24, E_, H3, 0);
  k_catbias<<<dim3(12), dim3(512), 0, stream>>>(bx1, bh1, b1cat);

  // ---- phase B: recurrence (WGs 0-31) + Wx1/Wh1 fp16 transposes (WGs 32-255) ----
  hipMemsetAsync(bar, 0, 131072, stream);
  {
    void* args[] = {(void*)&WhTf, (void*)&GX0, (void*)&bh0, (void*)&H0f, (void*)&H0last,
                    (void*)&bar, (void*)&Wx1, (void*)&Wh1, (void*)&BTf};
    hipLaunchCooperativeKernel((const void*)k_recur3, dim3(256), dim3(512), args, 0, stream);
  }

  // ---- phase C: layer 1, one fp16 GEMM per chunk (N = 6144) ----
  for (int chunk = 0; chunk < 2; ++chunk) {
    const _Float16* Ac = H0f + (size_t)chunk * 2048 * H_;
    k_gemm_f16<<<dim3(16 * 48), dim3(256), 0, stream>>>(
        Ac, BTf, b1cat, G1, 16, 48, H_, 6144, 0);
    k_gru1<<<dim3(2048), dim3(256), 0, stream>>>(G1, H0f, H1f, H1last, chunk * 2048);
  }

  // ---- phase D: FC via fp16 MFMA, 2 N-chunks of 16000, b-major epilogue remap ----
  for (int chunk = 0; chunk < 2; ++chunk) {
    const float* Wc = fcW + (size_t)chunk * 16000;
    k_transpose_f16<<<dim3(16000 / 32, H_ / 32), dim3(256), 0, stream>>>(Wc, V_, fcTf, H_);
    k_gemm_f16<<<dim3(32 * 125), dim3(256), 0, stream>>>(
        H1f, fcTf, fcb + (size_t)chunk * 16000,
        out + (size_t)chunk * 16000, 32, 125, H_, V_, 1);
  }

  // ---- final hidden ----
  k_hidden<<<dim3(32768 / 256), dim3(256), 0, stream>>>(H0last, H1last,
                                                        out + (size_t)B_ * T_ * V_);
}